// Round 13
// baseline (36.666 us; speedup 1.0000x reference)
//
#include <hip/hip_runtime.h>

#define A_N 32768
#define G_N 32
#define C_N 15
#define APB 128          // anchors per block
#define TPB 512          // threads per block (8 waves) -> 2 blocks/CU
#define H_N 4            // threads per anchor
#define BPB (A_N / APB)  // 256 blocks per batch
#define DEG2RAD ((float)(3.1415926 / 180.0))
#define BETA (1.0f / 9.0f)

typedef unsigned long long ull;

// One Sutherland-Hodgman clip pass, fully register-resident: all array
// indices are compile-time constants after unrolling; the output-compaction
// scatter is a static select chain bounded by m <= 2i(+1).
// Numerics match the reference: t = dc / (|denom|<1e-12 ? 1e-12 : denom).
template <int NIN>
__device__ __forceinline__ int clip_pass(float ax, float ay, float dx, float dy,
                                         float (&PX)[8], float (&PY)[8], int n) {
  constexpr int NOUT = (NIN + 1 < 8) ? NIN + 1 : 8;
  float d[NIN];
#pragma unroll
  for (int i = 0; i < NIN; ++i)
    d[i] = dx * (PY[i] - ay) - dy * (PX[i] - ax);
  float NX[NOUT], NY[NOUT];
#pragma unroll
  for (int i = 0; i < NOUT; ++i) { NX[i] = 0.f; NY[i] = 0.f; }
  int m = 0;
#pragma unroll
  for (int i = 0; i < NIN; ++i) {
    if (i < n) {
      bool w = (i + 1 < n);
      float dn = w ? d[(i + 1) % NIN] : d[0];
      float xn = w ? PX[(i + 1) % NIN] : PX[0];
      float yn = w ? PY[(i + 1) % NIN] : PY[0];
      bool kc = (d[i] >= 0.f);
      bool kn = (dn >= 0.f);
      if (kc) {
#pragma unroll
        for (int o = 0; o < NOUT; ++o)
          if (o <= 2 * i && m == o) { NX[o] = PX[i]; NY[o] = PY[i]; }
        ++m;
      }
      if (kc != kn) {
        float den = d[i] - dn;
        if (fabsf(den) < 1e-12f) den = 1e-12f;
        float t = d[i] / den;
        float ix = PX[i] + t * (xn - PX[i]);
        float iy = PY[i] + t * (yn - PY[i]);
#pragma unroll
        for (int o = 0; o < NOUT; ++o)
          if (o <= 2 * i + 1 && m == o) { NX[o] = ix; NY[o] = iy; }
        ++m;
      }
    }
  }
#pragma unroll
  for (int i = 0; i < NOUT; ++i) { PX[i] = NX[i]; PY[i] = NY[i]; }
#pragma unroll
  for (int i = NOUT; i < 8; ++i) { PX[i] = 0.f; PY[i] = 0.f; }
  return m;
}

// Fused geometry + (uncorrected) loss, 4 threads per anchor, 8 waves/block,
// 2 independent blocks per CU (independent barrier groups fill each other's
// stall slots). Forced-positive correction deferred to k_fix.
__global__ __launch_bounds__(TPB) void k_fused(
    const float* __restrict__ cls_in, const float* __restrict__ reg_in,
    const float* __restrict__ anchors, const float* __restrict__ annot,
    ull* __restrict__ gpart, ull* __restrict__ rowpack,
    float* __restrict__ cls_part, float* __restrict__ reg_part,
    int* __restrict__ cnt_part) {
  int j = blockIdx.x >> 8;          // 256 blocks per batch
  int blk = blockIdx.x & (BPB - 1);
  int tid = threadIdx.x;
  int la = tid & (APB - 1);   // anchor slot in block
  int h = tid >> 7;           // sub-thread 0..3 (uniform within each wave)
  int ln = tid & 63;          // lane in wave
  int a = blk * APB + la;
  size_t ia = (size_t)j * A_N + a;

  __shared__ float4 g_sqv[G_N];                 // gt min-area squares
  __shared__ float2 g_meta[G_N];                // (sarea, qarea)
  __shared__ float4 g_vx[G_N], g_vy[G_N];       // CCW gt quad verts
  __shared__ float4 a_qx[APB], a_qy[APB];       // anchor quads
  __shared__ float a_area[APB];
  __shared__ ull rowbest[APB];                  // packed (iou, ~g)
  __shared__ ull colmax[G_N];                   // packed (iou, ~a)
  __shared__ unsigned short list[APB * G_N];    // worst-case exact capacity
  __shared__ int cnt;
  __shared__ int lab[G_N];
  __shared__ float gcx[G_N], gcy[G_N], gw2[G_N], gh2[G_N], gth[G_N];
  __shared__ float w1[8], w2[8];
  __shared__ int w3[8];

  // prefetch loss inputs, vectorized (h splits the 15 classes 4/4/4/3;
  // h==3 uses float2+float to stay inside the array on the last row)
  float pcv[4];
  {
    const float* c = cls_in + ia * C_N;
    if (h < 3) {
      float4 v = *reinterpret_cast<const float4*>(c + h * 4);
      pcv[0] = v.x; pcv[1] = v.y; pcv[2] = v.z; pcv[3] = v.w;
    } else {
      float2 v = *reinterpret_cast<const float2*>(c + 12);
      pcv[0] = v.x; pcv[1] = v.y; pcv[2] = c[14]; pcv[3] = 0.f;
    }
  }
  float rvv[5];
  if (h == 0) {
    const float* r = reg_in + ia * 5;
    float4 v = *reinterpret_cast<const float4*>(r);
    rvv[0] = v.x; rvv[1] = v.y; rvv[2] = v.z; rvv[3] = v.w; rvv[4] = r[4];
  } else {
#pragma unroll
    for (int i = 0; i < 5; ++i) rvv[i] = 0.f;
  }

  if (tid == 0) cnt = 0;
  if (tid < APB) rowbest[tid] = 0xFFFFFFFFull;
  if (tid < G_N) colmax[tid] = 0xFFFFFFFFull;

  if (tid < G_N) {
    const float* g = annot + ((size_t)j * G_N + tid) * 6;
    float4 g0 = *reinterpret_cast<const float4*>(g);
    float2 g1 = *reinterpret_cast<const float2*>(g + 4);
    float x1 = g0.x, y1 = g0.y, x2 = g0.z, y2 = g0.w, t = g1.x;
    float cxx = (x1 + x2) * 0.5f, cyy = (y1 + y2) * 0.5f;
    float w = x2 - x1, hh = y2 - y1;
    gcx[tid] = cxx; gcy[tid] = cyy; gw2[tid] = w; gh2[tid] = hh; gth[tid] = t;
    lab[tid] = (int)g1.y;
    float th = t * DEG2RAD;
    float c = __cosf(th), s = __sinf(th);
    const float ddx[4] = {-0.5f, 0.5f, 0.5f, -0.5f};
    const float ddy[4] = {-0.5f, -0.5f, 0.5f, 0.5f};
    float px[4], py[4];
#pragma unroll
    for (int k = 0; k < 4; ++k) {
      px[k] = cxx + ddx[k] * w * c - ddy[k] * hh * s;
      py[k] = cyy + ddx[k] * w * s + ddy[k] * hh * c;
    }
    float s2 = 0.f;
#pragma unroll
    for (int k = 0; k < 4; ++k)
      s2 += px[k] * py[(k + 1) & 3] - px[(k + 1) & 3] * py[k];
    if (s2 < 0.f) {  // orient CCW (reference reverses)
      g_vx[tid] = make_float4(px[3], px[2], px[1], px[0]);
      g_vy[tid] = make_float4(py[3], py[2], py[1], py[0]);
    } else {
      g_vx[tid] = make_float4(px[0], px[1], px[2], px[3]);
      g_vy[tid] = make_float4(py[0], py[1], py[2], py[3]);
    }
    float half = fmaxf(w, hh) * 0.5f;
    float sx1 = cxx - half, sy1 = cyy - half, sx2 = cxx + half, sy2 = cyy + half;
    g_sqv[tid] = make_float4(sx1, sy1, sx2, sy2);
    g_meta[tid] = make_float2((sx2 - sx1) * (sy2 - sy1), 0.5f * fabsf(s2));
  }

  // anchor prep, vectorized load; all 4 sub-threads compute redundantly,
  // h==0 publishes
  const float* an = anchors + ia * 5;
  float4 av = *reinterpret_cast<const float4*>(an);
  float ax1 = av.x, ay1 = av.y, ax2 = av.z, ay2 = av.w, at = an[4];
  float acx = (ax1 + ax2) * 0.5f, acy = (ay1 + ay2) * 0.5f;
  float aw = ax2 - ax1, ah = ay2 - ay1;
  float ath = at * DEG2RAD;
  float ac = __cosf(ath), asn = __sinf(ath);
  {
    const float ddx[4] = {-0.5f, 0.5f, 0.5f, -0.5f};
    const float ddy[4] = {-0.5f, -0.5f, 0.5f, 0.5f};
    float apx[4], apy[4];
#pragma unroll
    for (int k = 0; k < 4; ++k) {
      apx[k] = acx + ddx[k] * aw * ac - ddy[k] * ah * asn;
      apy[k] = acy + ddx[k] * aw * asn + ddy[k] * ah * ac;
    }
    float s2a = 0.f;
#pragma unroll
    for (int k = 0; k < 4; ++k)
      s2a += apx[k] * apy[(k + 1) & 3] - apx[(k + 1) & 3] * apy[k];
    if (s2a < 0.f) {  // orient CCW (reference reverses)
      float tx = apx[0], ty = apy[0];
      apx[0] = apx[3]; apy[0] = apy[3]; apx[3] = tx; apy[3] = ty;
      tx = apx[1]; ty = apy[1];
      apx[1] = apx[2]; apy[1] = apy[2]; apx[2] = tx; apy[2] = ty;
    }
    if (h == 0) {
      a_qx[la] = make_float4(apx[0], apx[1], apx[2], apx[3]);
      a_qy[la] = make_float4(apy[0], apy[1], apy[2], apy[3]);
      a_area[la] = 0.5f * fabsf(s2a);
    }
  }
  float half = fmaxf(aw, ah) * 0.5f;
  float asx1 = acx - half, asy1 = acy - half, asx2 = acx + half, asy2 = acy + half;
  float asarea = (asx2 - asx1) * (asy2 - asy1);
  __syncthreads();

  // gate phase: h handles 8 of 32 GTs; ballot-compacted push (one atomic
  // per wave per iteration)
#pragma unroll
  for (int gg = 0; gg < G_N / H_N; ++gg) {
    int g = h * (G_N / H_N) + gg;
    float4 sq = g_sqv[g];
    float2 meta = g_meta[g];
    float ltx = fmaxf(asx1, sq.x);
    float lty = fmaxf(asy1, sq.y);
    float rbx = fminf(asx2, sq.z);
    float rby = fminf(asy2, sq.w);
    float iw = fmaxf(rbx - ltx, 0.f);
    float ih = fmaxf(rby - lty, 0.f);
    float inter_s = iw * ih;
    float ind = inter_s / (asarea + meta.x - inter_s + 1e-6f);
    float4 vx = g_vx[g], vy = g_vy[g];
    float cr0 = (vx.y - vx.x) * (acy - vy.x) - (vy.y - vy.x) * (acx - vx.x);
    float cr1 = (vx.z - vx.y) * (acy - vy.y) - (vy.z - vy.y) * (acx - vx.y);
    float cr2 = (vx.w - vx.z) * (acy - vy.z) - (vy.w - vy.z) * (acx - vx.z);
    float cr3 = (vx.x - vx.w) * (acy - vy.w) - (vy.x - vy.w) * (acx - vx.w);
    bool pall = (cr0 >= 0.f) & (cr1 >= 0.f) & (cr2 >= 0.f) & (cr3 >= 0.f);
    bool nall = (cr0 <= 0.f) & (cr1 <= 0.f) & (cr2 <= 0.f) & (cr3 <= 0.f);
    bool surv = (pall || nall) && (ind > 0.1f);
    ull bal = __ballot(surv);
    if (bal) {
      int base = 0;
      if (ln == 0) base = atomicAdd(&cnt, __popcll(bal));
      base = __shfl(base, 0);
      if (surv) {
        int pre = __popcll(bal & ((1ull << ln) - 1ull));
        list[base + pre] = (unsigned short)((la << 5) | g);
      }
    }
  }
  __syncthreads();

  // clip phase: drain queue densely across all 512 threads
  int np = cnt;
  for (int i = tid; i < np; i += TPB) {
    int ent = list[i];
    int ca = ent >> 5, g = ent & 31;
    float4 aqx = a_qx[ca], aqy = a_qy[ca];
    float PX[8], PY[8];
    PX[0] = aqx.x; PX[1] = aqx.y; PX[2] = aqx.z; PX[3] = aqx.w;
    PY[0] = aqy.x; PY[1] = aqy.y; PY[2] = aqy.z; PY[3] = aqy.w;
#pragma unroll
    for (int k = 4; k < 8; ++k) { PX[k] = 0.f; PY[k] = 0.f; }
    float4 gvx = g_vx[g], gvy = g_vy[g];
    int n = 4;
    n = clip_pass<4>(gvx.x, gvy.x, gvx.y - gvx.x, gvy.y - gvy.x, PX, PY, n);
    n = clip_pass<5>(gvx.y, gvy.y, gvx.z - gvx.y, gvy.z - gvy.y, PX, PY, n);
    n = clip_pass<6>(gvx.z, gvy.z, gvx.w - gvx.z, gvy.w - gvy.z, PX, PY, n);
    n = clip_pass<7>(gvx.w, gvy.w, gvx.x - gvx.w, gvy.x - gvy.w, PX, PY, n);
    float s = 0.f;
#pragma unroll
    for (int k = 0; k < 8; ++k) {
      if (k < n) {
        float xn = (k + 1 < n) ? PX[(k + 1) & 7] : PX[0];
        float yn = (k + 1 < n) ? PY[(k + 1) & 7] : PY[0];
        s += PX[k] * yn - xn * PY[k];
      }
    }
    float inter = (n >= 3) ? 0.5f * fabsf(s) : 0.f;
    float v = inter / (a_area[ca] + g_meta[g].y - inter + 1e-6f);
    ull pr = ((ull)__float_as_uint(v) << 32) | (unsigned)(~(unsigned)g);
    atomicMax(&rowbest[ca], pr);
    unsigned ga = (unsigned)(blk * APB + ca);
    ull pc = ((ull)__float_as_uint(v) << 32) | (unsigned)(~ga);
    atomicMax(&colmax[g], pc);
  }
  __syncthreads();

  ull rb = rowbest[la];
  float im = __uint_as_float((unsigned)(rb >> 32));
  int arg = (int)(~(unsigned)rb);  // low bits are ~g; init decodes to 0
  int p = (im >= 0.5f) ? 1 : 0;

  if (h == 0) rowpack[ia] = rb;  // for k_fix's forced-anchor delta
  if (tid < G_N)
    gpart[((size_t)j * BPB + blk) * G_N + tid] = colmax[tid];

  // ---- loss phase (uncorrected; fixup handles forced positives) ----
  int lb = lab[arg];
  float csum = 0.f;
  bool bg = (im < 0.4f);
  if (p || bg) {
#pragma unroll
    for (int k = 0; k < 4; ++k) {
      int ci = h * 4 + k;
      if (ci < C_N) {
        float pc = fminf(fmaxf(pcv[k], 1e-4f), 0.9999f);
        bool tgt1 = p && (ci == lb);
        if (tgt1)
          csum += 0.25f * (1.f - pc) * (1.f - pc) * (-__logf(pc + 1e-6f));
        else
          csum += 0.75f * pc * pc * (-__logf(1.f - pc + 1e-6f));
      }
    }
  }

  float rsum = 0.f;
  if (p && h == 0) {
    float t5[5];
    t5[0] = (gcx[arg] - acx) / aw;
    t5[1] = (gcy[arg] - acy) / ah;
    t5[2] = __logf(gw2[arg] / aw);
    t5[3] = __logf(gh2[arg] / ah);
    t5[4] = (gth[arg] - at) * DEG2RAD;
#pragma unroll
    for (int i = 0; i < 5; ++i) {
      float d = fabsf(rvv[i] - t5[i]);
      rsum += (d < BETA) ? (0.5f * d * d / BETA) : (d - 0.5f * BETA);
    }
  }
  int pcnt = (h == 0) ? p : 0;

  // wave shuffle-reduce, then 8 wave partials -> block partial
  float v1 = csum, v2 = rsum;
  int v3 = pcnt;
#pragma unroll
  for (int off = 32; off; off >>= 1) {
    v1 += __shfl_xor(v1, off);
    v2 += __shfl_xor(v2, off);
    v3 += __shfl_xor(v3, off);
  }
  int wv = tid >> 6;
  if (ln == 0) { w1[wv] = v1; w2[wv] = v2; w3[wv] = v3; }
  __syncthreads();
  if (tid == 0) {
    float t1 = 0.f, t2 = 0.f;
    int t3 = 0;
#pragma unroll
    for (int k = 0; k < 8; ++k) { t1 += w1[k]; t2 += w2[k]; t3 += w3[k]; }
    cls_part[blockIdx.x] = t1;
    reg_part[blockIdx.x] = t2;
    cnt_part[blockIdx.x] = t3;
  }
}

// Tiny fixup: resolve forced positives (column argmax over all blocks),
// apply exact per-anchor loss deltas, reduce partials, write output.
__global__ __launch_bounds__(256) void k_fix(
    const float* __restrict__ cls_in, const float* __restrict__ reg_in,
    const float* __restrict__ anchors, const float* __restrict__ annot,
    const ull* __restrict__ gpart, const ull* __restrict__ rowpack,
    const float* __restrict__ cls_part, const float* __restrict__ reg_part,
    const int* __restrict__ cnt_part, float* __restrict__ out, int B) {
  int tid = threadIdx.x;
  __shared__ ull sred[8][G_N];
  __shared__ int fanchor[G_N];
  __shared__ float dcs[G_N], drs[G_N];
  __shared__ int dct[G_N];
  __shared__ float bd_c[8], bd_r[8];  // per-batch delta sums (B<=8)
  __shared__ int bd_n[8];
  __shared__ float s1[256], s2[256];
  __shared__ int s3[256];

  for (int j = 0; j < B; ++j) {
    // reduce per-block column maxima: 8 chunks x 32 blocks per (g)
    {
      int g = tid & 31, chunk = tid >> 5;
      const ull* gp = gpart + (size_t)j * BPB * G_N;
      ull m = 0;
      for (int b = 0; b < BPB / 8; ++b) {
        ull v = gp[(size_t)(chunk * (BPB / 8) + b) * G_N + g];
        m = v > m ? v : m;
      }
      sred[chunk][g] = m;
    }
    __syncthreads();
    if (tid < G_N) {
      ull m = sred[0][tid];
#pragma unroll
      for (int c = 1; c < 8; ++c) m = sred[c][tid] > m ? sred[c][tid] : m;
      float v = __uint_as_float((unsigned)(m >> 32));
      fanchor[tid] = (v < 0.5f) ? (int)(~(unsigned)m) : -1;
      dcs[tid] = 0.f; drs[tid] = 0.f; dct[tid] = 0;
    }
    __syncthreads();
    if (tid < G_N) {
      int af = fanchor[tid];
      bool owner = (af >= 0);
      for (int g2 = 0; g2 < tid; ++g2)  // parallel dedup: first owner wins
        owner = owner && (fanchor[g2] != af);
      if (owner) {
        size_t ia = (size_t)j * A_N + af;
        ull rb = rowpack[ia];
        float im = __uint_as_float((unsigned)(rb >> 32));
        if (im < 0.5f) {  // p flips 0 -> 1: add exact loss delta
          int arg = (int)(~(unsigned)rb);
          const float* gg = annot + ((size_t)j * G_N + arg) * 6;
          int lb = (int)gg[5];
          const float* c = cls_in + ia * C_N;
          bool bg = (im < 0.4f);
          float ca = 0.f, cb = 0.f;
#pragma unroll
          for (int ci = 0; ci < C_N; ++ci) {
            float pc = fminf(fmaxf(c[ci], 1e-4f), 0.9999f);
            float neg = 0.75f * pc * pc * (-__logf(1.f - pc + 1e-6f));
            if (ci == lb)
              ca += 0.25f * (1.f - pc) * (1.f - pc) * (-__logf(pc + 1e-6f));
            else
              ca += neg;
            if (bg) cb += neg;
          }
          const float* an = anchors + ia * 5;
          float acx = (an[0] + an[2]) * 0.5f, acy = (an[1] + an[3]) * 0.5f;
          float aw = an[2] - an[0], ah = an[3] - an[1];
          float gcxv = (gg[0] + gg[2]) * 0.5f, gcyv = (gg[1] + gg[3]) * 0.5f;
          float gwv = gg[2] - gg[0], ghv = gg[3] - gg[1];
          const float* r = reg_in + ia * 5;
          float t5[5];
          t5[0] = (gcxv - acx) / aw;
          t5[1] = (gcyv - acy) / ah;
          t5[2] = __logf(gwv / aw);
          t5[3] = __logf(ghv / ah);
          t5[4] = (gg[4] - an[4]) * DEG2RAD;
          float rs = 0.f;
#pragma unroll
          for (int i = 0; i < 5; ++i) {
            float d = fabsf(r[i] - t5[i]);
            rs += (d < BETA) ? (0.5f * d * d / BETA) : (d - 0.5f * BETA);
          }
          dcs[tid] = ca - cb;
          drs[tid] = rs;
          dct[tid] = 1;
        }
      }
    }
    __syncthreads();
    if (tid == 0) {  // fixed-order delta sum
      float dc = 0.f, dr = 0.f;
      int dn = 0;
#pragma unroll
      for (int g = 0; g < G_N; ++g) { dc += dcs[g]; dr += drs[g]; dn += dct[g]; }
      bd_c[j] = dc; bd_r[j] = dr; bd_n[j] = dn;
    }
    __syncthreads();
  }

  // reduce per-block partials: B*BPB = 512 entries, 2 per thread.
  // threads 0..127 cover batch 0 (entries 0..255), 128..255 batch 1.
  int P = B * BPB;
  float cv = 0.f, rvv = 0.f;
  int nv = 0;
#pragma unroll
  for (int k = 0; k < 2; ++k) {
    int idx = tid * 2 + k;
    if (idx < P) { cv += cls_part[idx]; rvv += reg_part[idx]; nv += cnt_part[idx]; }
  }
  s1[tid] = cv; s2[tid] = rvv; s3[tid] = nv;
  __syncthreads();
  for (int o = 64; o; o >>= 1) {
    if ((tid & 127) < o) {
      s1[tid] += s1[tid + o]; s2[tid] += s2[tid + o]; s3[tid] += s3[tid + o];
    }
    __syncthreads();
  }
  if (tid == 0) {
    float cl = 0.f, rl = 0.f;
    for (int jj = 0; jj < B; ++jj) {
      float cs = s1[jj * 128] + bd_c[jj];
      float rs = s2[jj * 128] + bd_r[jj];
      int np = s3[jj * 128] + bd_n[jj];
      float npf = (np > 0) ? (float)np : 1.f;
      cl += cs / npf;
      rl += (np > 0) ? rs / (npf * 5.f) : 0.f;
    }
    out[0] = 5.0f * cl / (float)B;
    out[1] = 2.0f * rl / (float)B;
  }
}

extern "C" void kernel_launch(void* const* d_in, const int* in_sizes, int n_in,
                              void* d_out, int out_size, void* d_ws, size_t ws_size,
                              hipStream_t stream) {
  const float* cls = (const float*)d_in[0];
  const float* reg = (const float*)d_in[1];
  const float* anc = (const float*)d_in[2];
  const float* ann = (const float*)d_in[3];
  int B = in_sizes[3] / (G_N * 6);

  char* w = (char*)d_ws;
  ull* gpart = (ull*)w;        w += (size_t)B * BPB * G_N * sizeof(ull);
  ull* rowpack = (ull*)w;      w += (size_t)B * A_N * sizeof(ull);
  float* cls_part = (float*)w; w += (size_t)B * BPB * 4;
  float* reg_part = (float*)w; w += (size_t)B * BPB * 4;
  int* cnt_part = (int*)w;     w += (size_t)B * BPB * 4;

  k_fused<<<B * BPB, TPB, 0, stream>>>(cls, reg, anc, ann, gpart, rowpack,
                                       cls_part, reg_part, cnt_part);
  k_fix<<<1, 256, 0, stream>>>(cls, reg, anc, ann, gpart, rowpack,
                               cls_part, reg_part, cnt_part, (float*)d_out, B);
}

// Round 14
// 35.450 us; speedup vs baseline: 1.0343x; 1.0343x over previous
//
#include <hip/hip_runtime.h>

#define A_N 32768
#define G_N 32
#define C_N 15
#define APB 256          // anchors per block
#define TPB 1024         // threads per block (16 waves, 4/SIMD)
#define H_N 4            // threads per anchor
#define BPB (A_N / APB)  // 128 blocks per batch
#define DEG2RAD ((float)(3.1415926 / 180.0))
#define BETA (1.0f / 9.0f)

typedef unsigned long long ull;

// One Sutherland-Hodgman clip pass, fully register-resident: all array
// indices are compile-time constants after unrolling; the output-compaction
// scatter is a static select chain bounded by m <= 2i(+1).
// Numerics match the reference: t = dc / (|denom|<1e-12 ? 1e-12 : denom).
template <int NIN>
__device__ __forceinline__ int clip_pass(float ax, float ay, float dx, float dy,
                                         float (&PX)[8], float (&PY)[8], int n) {
  constexpr int NOUT = (NIN + 1 < 8) ? NIN + 1 : 8;
  float d[NIN];
#pragma unroll
  for (int i = 0; i < NIN; ++i)
    d[i] = dx * (PY[i] - ay) - dy * (PX[i] - ax);
  float NX[NOUT], NY[NOUT];
#pragma unroll
  for (int i = 0; i < NOUT; ++i) { NX[i] = 0.f; NY[i] = 0.f; }
  int m = 0;
#pragma unroll
  for (int i = 0; i < NIN; ++i) {
    if (i < n) {
      bool w = (i + 1 < n);
      float dn = w ? d[(i + 1) % NIN] : d[0];
      float xn = w ? PX[(i + 1) % NIN] : PX[0];
      float yn = w ? PY[(i + 1) % NIN] : PY[0];
      bool kc = (d[i] >= 0.f);
      bool kn = (dn >= 0.f);
      if (kc) {
#pragma unroll
        for (int o = 0; o < NOUT; ++o)
          if (o <= 2 * i && m == o) { NX[o] = PX[i]; NY[o] = PY[i]; }
        ++m;
      }
      if (kc != kn) {
        float den = d[i] - dn;
        if (fabsf(den) < 1e-12f) den = 1e-12f;
        float t = d[i] / den;
        float ix = PX[i] + t * (xn - PX[i]);
        float iy = PY[i] + t * (yn - PY[i]);
#pragma unroll
        for (int o = 0; o < NOUT; ++o)
          if (o <= 2 * i + 1 && m == o) { NX[o] = ix; NY[o] = iy; }
        ++m;
      }
    }
  }
#pragma unroll
  for (int i = 0; i < NOUT; ++i) { PX[i] = NX[i]; PY[i] = NY[i]; }
#pragma unroll
  for (int i = NOUT; i < 8; ++i) { PX[i] = 0.f; PY[i] = 0.f; }
  return m;
}

// Fused geometry + (uncorrected) loss, 4 threads per anchor.
// Forced-positive correction (only cross-block dependency) deferred to k_fix.
__global__ __launch_bounds__(TPB) void k_fused(
    const float* __restrict__ cls_in, const float* __restrict__ reg_in,
    const float* __restrict__ anchors, const float* __restrict__ annot,
    ull* __restrict__ gpart, ull* __restrict__ rowpack,
    float* __restrict__ cls_part, float* __restrict__ reg_part,
    int* __restrict__ cnt_part) {
  int j = blockIdx.x >> 7;
  int blk = blockIdx.x & (BPB - 1);
  int tid = threadIdx.x;
  int la = tid & (APB - 1);   // anchor slot in block
  int h = tid >> 8;           // sub-thread 0..3 (wave-uniform)
  int ln = tid & 63;          // lane in wave
  int a = blk * APB + la;
  size_t ia = (size_t)j * A_N + a;

  __shared__ float4 g_sqv[G_N];                 // gt min-area squares
  __shared__ float2 g_meta[G_N];                // (sarea, qarea)
  __shared__ float4 g_vx[G_N], g_vy[G_N];       // CCW gt quad verts
  __shared__ float4 a_qx[APB], a_qy[APB];       // anchor quads
  __shared__ float a_area[APB];
  __shared__ ull rowbest[APB];                  // packed (iou, ~g)
  __shared__ ull colmax[G_N];                   // packed (iou, ~a)
  __shared__ unsigned short list[APB * G_N];    // worst-case exact capacity
  __shared__ int cnt;
  __shared__ int lab[G_N];
  __shared__ float gcx[G_N], gcy[G_N], gw2[G_N], gh2[G_N], gth[G_N];
  __shared__ float w1[16], w2[16];
  __shared__ int w3[16];

  // prefetch loss inputs, vectorized (h splits the 15 classes 4/4/4/3;
  // h==3 uses float2+float to stay inside the array on the last row)
  float pcv[4];
  {
    const float* c = cls_in + ia * C_N;
    if (h < 3) {
      float4 v = *reinterpret_cast<const float4*>(c + h * 4);
      pcv[0] = v.x; pcv[1] = v.y; pcv[2] = v.z; pcv[3] = v.w;
    } else {
      float2 v = *reinterpret_cast<const float2*>(c + 12);
      pcv[0] = v.x; pcv[1] = v.y; pcv[2] = c[14]; pcv[3] = 0.f;
    }
  }
  float rvv[5];
  if (h == 0) {
    const float* r = reg_in + ia * 5;
    float4 v = *reinterpret_cast<const float4*>(r);
    rvv[0] = v.x; rvv[1] = v.y; rvv[2] = v.z; rvv[3] = v.w; rvv[4] = r[4];
  } else {
#pragma unroll
    for (int i = 0; i < 5; ++i) rvv[i] = 0.f;
  }

  if (tid == 0) cnt = 0;
  if (tid < APB) rowbest[tid] = 0xFFFFFFFFull;
  if (tid < G_N) colmax[tid] = 0xFFFFFFFFull;

  if (tid < G_N) {
    const float* g = annot + ((size_t)j * G_N + tid) * 6;
    float4 g0 = *reinterpret_cast<const float4*>(g);
    float2 g1 = *reinterpret_cast<const float2*>(g + 4);
    float x1 = g0.x, y1 = g0.y, x2 = g0.z, y2 = g0.w, t = g1.x;
    float cxx = (x1 + x2) * 0.5f, cyy = (y1 + y2) * 0.5f;
    float w = x2 - x1, hh = y2 - y1;
    gcx[tid] = cxx; gcy[tid] = cyy; gw2[tid] = w; gh2[tid] = hh; gth[tid] = t;
    lab[tid] = (int)g1.y;
    float th = t * DEG2RAD;
    float c = __cosf(th), s = __sinf(th);
    const float ddx[4] = {-0.5f, 0.5f, 0.5f, -0.5f};
    const float ddy[4] = {-0.5f, -0.5f, 0.5f, 0.5f};
    float px[4], py[4];
#pragma unroll
    for (int k = 0; k < 4; ++k) {
      px[k] = cxx + ddx[k] * w * c - ddy[k] * hh * s;
      py[k] = cyy + ddx[k] * w * s + ddy[k] * hh * c;
    }
    float s2 = 0.f;
#pragma unroll
    for (int k = 0; k < 4; ++k)
      s2 += px[k] * py[(k + 1) & 3] - px[(k + 1) & 3] * py[k];
    if (s2 < 0.f) {  // orient CCW (reference reverses)
      g_vx[tid] = make_float4(px[3], px[2], px[1], px[0]);
      g_vy[tid] = make_float4(py[3], py[2], py[1], py[0]);
    } else {
      g_vx[tid] = make_float4(px[0], px[1], px[2], px[3]);
      g_vy[tid] = make_float4(py[0], py[1], py[2], py[3]);
    }
    float half = fmaxf(w, hh) * 0.5f;
    float sx1 = cxx - half, sy1 = cyy - half, sx2 = cxx + half, sy2 = cyy + half;
    g_sqv[tid] = make_float4(sx1, sy1, sx2, sy2);
    g_meta[tid] = make_float2((sx2 - sx1) * (sy2 - sy1), 0.5f * fabsf(s2));
  }

  // anchor prep, vectorized load; all 4 sub-threads compute redundantly,
  // h==0 publishes
  const float* an = anchors + ia * 5;
  float4 av = *reinterpret_cast<const float4*>(an);
  float ax1 = av.x, ay1 = av.y, ax2 = av.z, ay2 = av.w, at = an[4];
  float acx = (ax1 + ax2) * 0.5f, acy = (ay1 + ay2) * 0.5f;
  float aw = ax2 - ax1, ah = ay2 - ay1;
  float ath = at * DEG2RAD;
  float ac = __cosf(ath), asn = __sinf(ath);
  {
    const float ddx[4] = {-0.5f, 0.5f, 0.5f, -0.5f};
    const float ddy[4] = {-0.5f, -0.5f, 0.5f, 0.5f};
    float apx[4], apy[4];
#pragma unroll
    for (int k = 0; k < 4; ++k) {
      apx[k] = acx + ddx[k] * aw * ac - ddy[k] * ah * asn;
      apy[k] = acy + ddx[k] * aw * asn + ddy[k] * ah * ac;
    }
    float s2a = 0.f;
#pragma unroll
    for (int k = 0; k < 4; ++k)
      s2a += apx[k] * apy[(k + 1) & 3] - apx[(k + 1) & 3] * apy[k];
    if (s2a < 0.f) {  // orient CCW (reference reverses)
      float tx = apx[0], ty = apy[0];
      apx[0] = apx[3]; apy[0] = apy[3]; apx[3] = tx; apy[3] = ty;
      tx = apx[1]; ty = apy[1];
      apx[1] = apx[2]; apy[1] = apy[2]; apx[2] = tx; apy[2] = ty;
    }
    if (h == 0) {
      a_qx[la] = make_float4(apx[0], apx[1], apx[2], apx[3]);
      a_qy[la] = make_float4(apy[0], apy[1], apy[2], apy[3]);
      a_area[la] = 0.5f * fabsf(s2a);
    }
  }
  float half = fmaxf(aw, ah) * 0.5f;
  float asx1 = acx - half, asy1 = acy - half, asx2 = acx + half, asy2 = acy + half;
  float asarea = (asx2 - asx1) * (asy2 - asy1);
  __syncthreads();

  // gate phase: h handles 8 of 32 GTs; ballot-compacted push (one atomic
  // per wave per iteration instead of ~per-survivor same-address atomics)
#pragma unroll
  for (int gg = 0; gg < G_N / H_N; ++gg) {
    int g = h * (G_N / H_N) + gg;
    float4 sq = g_sqv[g];
    float2 meta = g_meta[g];
    float ltx = fmaxf(asx1, sq.x);
    float lty = fmaxf(asy1, sq.y);
    float rbx = fminf(asx2, sq.z);
    float rby = fminf(asy2, sq.w);
    float iw = fmaxf(rbx - ltx, 0.f);
    float ih = fmaxf(rby - lty, 0.f);
    float inter_s = iw * ih;
    float ind = inter_s / (asarea + meta.x - inter_s + 1e-6f);
    float4 vx = g_vx[g], vy = g_vy[g];
    float cr0 = (vx.y - vx.x) * (acy - vy.x) - (vy.y - vy.x) * (acx - vx.x);
    float cr1 = (vx.z - vx.y) * (acy - vy.y) - (vy.z - vy.y) * (acx - vx.y);
    float cr2 = (vx.w - vx.z) * (acy - vy.z) - (vy.w - vy.z) * (acx - vx.z);
    float cr3 = (vx.x - vx.w) * (acy - vy.w) - (vy.x - vy.w) * (acx - vx.w);
    bool pall = (cr0 >= 0.f) & (cr1 >= 0.f) & (cr2 >= 0.f) & (cr3 >= 0.f);
    bool nall = (cr0 <= 0.f) & (cr1 <= 0.f) & (cr2 <= 0.f) & (cr3 <= 0.f);
    bool surv = (pall || nall) && (ind > 0.1f);
    ull bal = __ballot(surv);
    if (bal) {
      int base = 0;
      if (ln == 0) base = atomicAdd(&cnt, __popcll(bal));
      base = __shfl(base, 0);
      if (surv) {
        int pre = __popcll(bal & ((1ull << ln) - 1ull));
        list[base + pre] = (unsigned short)((la << 5) | g);
      }
    }
  }
  __syncthreads();

  // clip phase: drain queue densely across all 1024 threads
  int np = cnt;
  for (int i = tid; i < np; i += TPB) {
    int ent = list[i];
    int ca = ent >> 5, g = ent & 31;
    float4 aqx = a_qx[ca], aqy = a_qy[ca];
    float PX[8], PY[8];
    PX[0] = aqx.x; PX[1] = aqx.y; PX[2] = aqx.z; PX[3] = aqx.w;
    PY[0] = aqy.x; PY[1] = aqy.y; PY[2] = aqy.z; PY[3] = aqy.w;
#pragma unroll
    for (int k = 4; k < 8; ++k) { PX[k] = 0.f; PY[k] = 0.f; }
    float4 gvx = g_vx[g], gvy = g_vy[g];
    int n = 4;
    n = clip_pass<4>(gvx.x, gvy.x, gvx.y - gvx.x, gvy.y - gvy.x, PX, PY, n);
    n = clip_pass<5>(gvx.y, gvy.y, gvx.z - gvx.y, gvy.z - gvy.y, PX, PY, n);
    n = clip_pass<6>(gvx.z, gvy.z, gvx.w - gvx.z, gvy.w - gvy.z, PX, PY, n);
    n = clip_pass<7>(gvx.w, gvy.w, gvx.x - gvx.w, gvy.x - gvy.w, PX, PY, n);
    float s = 0.f;
#pragma unroll
    for (int k = 0; k < 8; ++k) {
      if (k < n) {
        float xn = (k + 1 < n) ? PX[(k + 1) & 7] : PX[0];
        float yn = (k + 1 < n) ? PY[(k + 1) & 7] : PY[0];
        s += PX[k] * yn - xn * PY[k];
      }
    }
    float inter = (n >= 3) ? 0.5f * fabsf(s) : 0.f;
    float v = inter / (a_area[ca] + g_meta[g].y - inter + 1e-6f);
    ull pr = ((ull)__float_as_uint(v) << 32) | (unsigned)(~(unsigned)g);
    atomicMax(&rowbest[ca], pr);
    unsigned ga = (unsigned)(blk * APB + ca);
    ull pc = ((ull)__float_as_uint(v) << 32) | (unsigned)(~ga);
    atomicMax(&colmax[g], pc);
  }
  __syncthreads();

  ull rb = rowbest[la];
  float im = __uint_as_float((unsigned)(rb >> 32));
  int arg = (int)(~(unsigned)rb);  // low bits are ~g; init decodes to 0
  int p = (im >= 0.5f) ? 1 : 0;

  if (h == 0) rowpack[ia] = rb;  // for k_fix's forced-anchor delta
  if (tid < G_N)
    gpart[((size_t)j * BPB + blk) * G_N + tid] = colmax[tid];

  // ---- loss phase (uncorrected; fixup handles forced positives) ----
  int lb = lab[arg];
  float csum = 0.f;
  bool bg = (im < 0.4f);
  if (p || bg) {
#pragma unroll
    for (int k = 0; k < 4; ++k) {
      int ci = h * 4 + k;
      if (ci < C_N) {
        float pc = fminf(fmaxf(pcv[k], 1e-4f), 0.9999f);
        bool tgt1 = p && (ci == lb);
        if (tgt1)
          csum += 0.25f * (1.f - pc) * (1.f - pc) * (-__logf(pc + 1e-6f));
        else
          csum += 0.75f * pc * pc * (-__logf(1.f - pc + 1e-6f));
      }
    }
  }

  float rsum = 0.f;
  if (p && h == 0) {
    float t5[5];
    t5[0] = (gcx[arg] - acx) / aw;
    t5[1] = (gcy[arg] - acy) / ah;
    t5[2] = __logf(gw2[arg] / aw);
    t5[3] = __logf(gh2[arg] / ah);
    t5[4] = (gth[arg] - at) * DEG2RAD;
#pragma unroll
    for (int i = 0; i < 5; ++i) {
      float d = fabsf(rvv[i] - t5[i]);
      rsum += (d < BETA) ? (0.5f * d * d / BETA) : (d - 0.5f * BETA);
    }
  }
  int pcnt = (h == 0) ? p : 0;

  // wave shuffle-reduce, then 16 wave partials -> block partial
  float v1 = csum, v2 = rsum;
  int v3 = pcnt;
#pragma unroll
  for (int off = 32; off; off >>= 1) {
    v1 += __shfl_xor(v1, off);
    v2 += __shfl_xor(v2, off);
    v3 += __shfl_xor(v3, off);
  }
  int wv = tid >> 6;
  if (ln == 0) { w1[wv] = v1; w2[wv] = v2; w3[wv] = v3; }
  __syncthreads();
  if (tid == 0) {
    float t1 = 0.f, t2 = 0.f;
    int t3 = 0;
#pragma unroll
    for (int k = 0; k < 16; ++k) { t1 += w1[k]; t2 += w2[k]; t3 += w3[k]; }
    cls_part[blockIdx.x] = t1;
    reg_part[blockIdx.x] = t2;
    cnt_part[blockIdx.x] = t3;
  }
}

// Tiny fixup: resolve forced positives (column argmax over all blocks),
// apply exact per-anchor loss deltas, reduce partials, write output.
// 1024 threads: stage-A's cross-XCD loads get 4x the memory-level
// parallelism (4 loads/thread instead of 16).
__global__ __launch_bounds__(1024) void k_fix(
    const float* __restrict__ cls_in, const float* __restrict__ reg_in,
    const float* __restrict__ anchors, const float* __restrict__ annot,
    const ull* __restrict__ gpart, const ull* __restrict__ rowpack,
    const float* __restrict__ cls_part, const float* __restrict__ reg_part,
    const int* __restrict__ cnt_part, float* __restrict__ out, int B) {
  int tid = threadIdx.x;
  __shared__ ull sred[32][G_N];
  __shared__ int fanchor[G_N];
  __shared__ float dcs[G_N], drs[G_N];
  __shared__ int dct[G_N];
  __shared__ float bd_c[8], bd_r[8];  // per-batch delta sums (B<=8)
  __shared__ int bd_n[8];
  __shared__ float s1[256], s2[256];
  __shared__ int s3[256];

  for (int j = 0; j < B; ++j) {
    // stage A: 32 chunks x 4 blocks per (g); 4 independent loads/thread
    {
      int g = tid & 31, chunk = tid >> 5;
      const ull* gp = gpart + (size_t)j * BPB * G_N;
      ull m = 0;
#pragma unroll
      for (int b = 0; b < BPB / 32; ++b) {
        ull v = gp[(size_t)(chunk * (BPB / 32) + b) * G_N + g];
        m = v > m ? v : m;
      }
      sred[chunk][g] = m;
    }
    __syncthreads();
    if (tid < G_N) {
      ull m = sred[0][tid];
#pragma unroll
      for (int c = 1; c < 32; ++c) m = sred[c][tid] > m ? sred[c][tid] : m;
      float v = __uint_as_float((unsigned)(m >> 32));
      fanchor[tid] = (v < 0.5f) ? (int)(~(unsigned)m) : -1;
      dcs[tid] = 0.f; drs[tid] = 0.f; dct[tid] = 0;
    }
    __syncthreads();
    if (tid < G_N) {
      int af = fanchor[tid];
      bool owner = (af >= 0);
      for (int g2 = 0; g2 < tid; ++g2)  // parallel dedup: first owner wins
        owner = owner && (fanchor[g2] != af);
      if (owner) {
        size_t ia = (size_t)j * A_N + af;
        ull rb = rowpack[ia];
        float im = __uint_as_float((unsigned)(rb >> 32));
        if (im < 0.5f) {  // p flips 0 -> 1: add exact loss delta
          int arg = (int)(~(unsigned)rb);
          const float* gg = annot + ((size_t)j * G_N + arg) * 6;
          int lb = (int)gg[5];
          const float* c = cls_in + ia * C_N;
          bool bg = (im < 0.4f);
          float ca = 0.f, cb = 0.f;
#pragma unroll
          for (int ci = 0; ci < C_N; ++ci) {
            float pc = fminf(fmaxf(c[ci], 1e-4f), 0.9999f);
            float neg = 0.75f * pc * pc * (-__logf(1.f - pc + 1e-6f));
            if (ci == lb)
              ca += 0.25f * (1.f - pc) * (1.f - pc) * (-__logf(pc + 1e-6f));
            else
              ca += neg;
            if (bg) cb += neg;
          }
          const float* an = anchors + ia * 5;
          float acx = (an[0] + an[2]) * 0.5f, acy = (an[1] + an[3]) * 0.5f;
          float aw = an[2] - an[0], ah = an[3] - an[1];
          float gcxv = (gg[0] + gg[2]) * 0.5f, gcyv = (gg[1] + gg[3]) * 0.5f;
          float gwv = gg[2] - gg[0], ghv = gg[3] - gg[1];
          const float* r = reg_in + ia * 5;
          float t5[5];
          t5[0] = (gcxv - acx) / aw;
          t5[1] = (gcyv - acy) / ah;
          t5[2] = __logf(gwv / aw);
          t5[3] = __logf(ghv / ah);
          t5[4] = (gg[4] - an[4]) * DEG2RAD;
          float rs = 0.f;
#pragma unroll
          for (int i = 0; i < 5; ++i) {
            float d = fabsf(r[i] - t5[i]);
            rs += (d < BETA) ? (0.5f * d * d / BETA) : (d - 0.5f * BETA);
          }
          dcs[tid] = ca - cb;
          drs[tid] = rs;
          dct[tid] = 1;
        }
      }
    }
    __syncthreads();
    if (tid == 0) {  // fixed-order delta sum
      float dc = 0.f, dr = 0.f;
      int dn = 0;
#pragma unroll
      for (int g = 0; g < G_N; ++g) { dc += dcs[g]; dr += drs[g]; dn += dct[g]; }
      bd_c[j] = dc; bd_r[j] = dr; bd_n[j] = dn;
    }
    __syncthreads();
  }

  // reduce per-block partials (B*BPB <= 256 entries; first 256 threads)
  int P = B * BPB;
  if (tid < 256) {
    float cv = 0.f, rvv = 0.f;
    int nv = 0;
    if (tid < P) { cv = cls_part[tid]; rvv = reg_part[tid]; nv = cnt_part[tid]; }
    s1[tid] = cv; s2[tid] = rvv; s3[tid] = nv;
  }
  __syncthreads();
  for (int o = 64; o; o >>= 1) {
    if (tid < 256 && (tid & 127) < o) {
      s1[tid] += s1[tid + o]; s2[tid] += s2[tid + o]; s3[tid] += s3[tid + o];
    }
    __syncthreads();
  }
  if (tid == 0) {
    float cl = 0.f, rl = 0.f;
    for (int jj = 0; jj < B; ++jj) {
      float cs = s1[jj * 128] + bd_c[jj];
      float rs = s2[jj * 128] + bd_r[jj];
      int np = s3[jj * 128] + bd_n[jj];
      float npf = (np > 0) ? (float)np : 1.f;
      cl += cs / npf;
      rl += (np > 0) ? rs / (npf * 5.f) : 0.f;
    }
    out[0] = 5.0f * cl / (float)B;
    out[1] = 2.0f * rl / (float)B;
  }
}

extern "C" void kernel_launch(void* const* d_in, const int* in_sizes, int n_in,
                              void* d_out, int out_size, void* d_ws, size_t ws_size,
                              hipStream_t stream) {
  const float* cls = (const float*)d_in[0];
  const float* reg = (const float*)d_in[1];
  const float* anc = (const float*)d_in[2];
  const float* ann = (const float*)d_in[3];
  int B = in_sizes[3] / (G_N * 6);

  char* w = (char*)d_ws;
  ull* gpart = (ull*)w;        w += (size_t)B * BPB * G_N * sizeof(ull);
  ull* rowpack = (ull*)w;      w += (size_t)B * A_N * sizeof(ull);
  float* cls_part = (float*)w; w += (size_t)B * BPB * 4;
  float* reg_part = (float*)w; w += (size_t)B * BPB * 4;
  int* cnt_part = (int*)w;     w += (size_t)B * BPB * 4;

  k_fused<<<B * BPB, TPB, 0, stream>>>(cls, reg, anc, ann, gpart, rowpack,
                                       cls_part, reg_part, cnt_part);
  k_fix<<<1, 1024, 0, stream>>>(cls, reg, anc, ann, gpart, rowpack,
                                cls_part, reg_part, cnt_part, (float*)d_out, B);
}

// Round 15
// 34.360 us; speedup vs baseline: 1.0671x; 1.0317x over previous
//
#include <hip/hip_runtime.h>

#define A_N 32768
#define G_N 32
#define C_N 15
#define APB 256          // anchors per block
#define TPB 1024         // threads per block (16 waves, 4/SIMD)
#define H_N 4            // threads per anchor
#define BPB (A_N / APB)  // 128 blocks per batch
#define DEG2RAD ((float)(3.1415926 / 180.0))
#define BETA (1.0f / 9.0f)

typedef unsigned long long ull;

// One Sutherland-Hodgman clip pass, fully register-resident: all array
// indices are compile-time constants after unrolling; the output-compaction
// scatter is a static select chain bounded by m <= 2i(+1).
// Numerics match the reference: t = dc / (|denom|<1e-12 ? 1e-12 : denom).
template <int NIN>
__device__ __forceinline__ int clip_pass(float ax, float ay, float dx, float dy,
                                         float (&PX)[8], float (&PY)[8], int n) {
  constexpr int NOUT = (NIN + 1 < 8) ? NIN + 1 : 8;
  float d[NIN];
#pragma unroll
  for (int i = 0; i < NIN; ++i)
    d[i] = dx * (PY[i] - ay) - dy * (PX[i] - ax);
  float NX[NOUT], NY[NOUT];
#pragma unroll
  for (int i = 0; i < NOUT; ++i) { NX[i] = 0.f; NY[i] = 0.f; }
  int m = 0;
#pragma unroll
  for (int i = 0; i < NIN; ++i) {
    if (i < n) {
      bool w = (i + 1 < n);
      float dn = w ? d[(i + 1) % NIN] : d[0];
      float xn = w ? PX[(i + 1) % NIN] : PX[0];
      float yn = w ? PY[(i + 1) % NIN] : PY[0];
      bool kc = (d[i] >= 0.f);
      bool kn = (dn >= 0.f);
      if (kc) {
#pragma unroll
        for (int o = 0; o < NOUT; ++o)
          if (o <= 2 * i && m == o) { NX[o] = PX[i]; NY[o] = PY[i]; }
        ++m;
      }
      if (kc != kn) {
        float den = d[i] - dn;
        if (fabsf(den) < 1e-12f) den = 1e-12f;
        float t = d[i] / den;
        float ix = PX[i] + t * (xn - PX[i]);
        float iy = PY[i] + t * (yn - PY[i]);
#pragma unroll
        for (int o = 0; o < NOUT; ++o)
          if (o <= 2 * i + 1 && m == o) { NX[o] = ix; NY[o] = iy; }
        ++m;
      }
    }
  }
#pragma unroll
  for (int i = 0; i < NOUT; ++i) { PX[i] = NX[i]; PY[i] = NY[i]; }
#pragma unroll
  for (int i = NOUT; i < 8; ++i) { PX[i] = 0.f; PY[i] = 0.f; }
  return m;
}

// Fused geometry + (uncorrected) loss, 4 threads per anchor.
// Forced-positive correction (only cross-block dependency) deferred to k_fix.
__global__ __launch_bounds__(TPB) void k_fused(
    const float* __restrict__ cls_in, const float* __restrict__ reg_in,
    const float* __restrict__ anchors, const float* __restrict__ annot,
    ull* __restrict__ gpart, ull* __restrict__ rowpack,
    float* __restrict__ cls_part, float* __restrict__ reg_part,
    int* __restrict__ cnt_part) {
  int j = blockIdx.x >> 7;
  int blk = blockIdx.x & (BPB - 1);
  int tid = threadIdx.x;
  int la = tid & (APB - 1);   // anchor slot in block
  int h = tid >> 8;           // sub-thread 0..3 (wave-uniform)
  int ln = tid & 63;          // lane in wave
  int a = blk * APB + la;
  size_t ia = (size_t)j * A_N + a;

  __shared__ float4 g_sqv[G_N];                 // gt min-area squares
  __shared__ float2 g_meta[G_N];                // (sarea, qarea)
  __shared__ float4 g_vx[G_N], g_vy[G_N];       // CCW gt quad verts
  __shared__ float4 a_qx[APB], a_qy[APB];       // anchor quads
  __shared__ float a_area[APB];
  __shared__ ull rowbest[APB];                  // packed (iou, ~g)
  __shared__ ull colmax[G_N];                   // packed (iou, ~a)
  __shared__ unsigned short list[APB * G_N];    // worst-case exact capacity
  __shared__ int cnt;
  __shared__ int lab[G_N];
  __shared__ float gcx[G_N], gcy[G_N], gw2[G_N], gh2[G_N], gth[G_N];
  __shared__ float w1[16], w2[16];
  __shared__ int w3[16];

  // prefetch loss inputs, vectorized (h splits the 15 classes 4/4/4/3;
  // h==3 uses float2+float to stay inside the array on the last row)
  float pcv[4];
  {
    const float* c = cls_in + ia * C_N;
    if (h < 3) {
      float4 v = *reinterpret_cast<const float4*>(c + h * 4);
      pcv[0] = v.x; pcv[1] = v.y; pcv[2] = v.z; pcv[3] = v.w;
    } else {
      float2 v = *reinterpret_cast<const float2*>(c + 12);
      pcv[0] = v.x; pcv[1] = v.y; pcv[2] = c[14]; pcv[3] = 0.f;
    }
  }
  float rvv[5];
  if (h == 0) {
    const float* r = reg_in + ia * 5;
    float4 v = *reinterpret_cast<const float4*>(r);
    rvv[0] = v.x; rvv[1] = v.y; rvv[2] = v.z; rvv[3] = v.w; rvv[4] = r[4];
  } else {
#pragma unroll
    for (int i = 0; i < 5; ++i) rvv[i] = 0.f;
  }

  if (tid == 0) cnt = 0;
  if (tid < APB) rowbest[tid] = 0xFFFFFFFFull;
  if (tid < G_N) colmax[tid] = 0xFFFFFFFFull;

  if (tid < G_N) {
    const float* g = annot + ((size_t)j * G_N + tid) * 6;
    float4 g0 = *reinterpret_cast<const float4*>(g);
    float2 g1 = *reinterpret_cast<const float2*>(g + 4);
    float x1 = g0.x, y1 = g0.y, x2 = g0.z, y2 = g0.w, t = g1.x;
    float cxx = (x1 + x2) * 0.5f, cyy = (y1 + y2) * 0.5f;
    float w = x2 - x1, hh = y2 - y1;
    gcx[tid] = cxx; gcy[tid] = cyy; gw2[tid] = w; gh2[tid] = hh; gth[tid] = t;
    lab[tid] = (int)g1.y;
    float th = t * DEG2RAD;
    float c = __cosf(th), s = __sinf(th);
    const float ddx[4] = {-0.5f, 0.5f, 0.5f, -0.5f};
    const float ddy[4] = {-0.5f, -0.5f, 0.5f, 0.5f};
    float px[4], py[4];
#pragma unroll
    for (int k = 0; k < 4; ++k) {
      px[k] = cxx + ddx[k] * w * c - ddy[k] * hh * s;
      py[k] = cyy + ddx[k] * w * s + ddy[k] * hh * c;
    }
    float s2 = 0.f;
#pragma unroll
    for (int k = 0; k < 4; ++k)
      s2 += px[k] * py[(k + 1) & 3] - px[(k + 1) & 3] * py[k];
    if (s2 < 0.f) {  // orient CCW (reference reverses)
      g_vx[tid] = make_float4(px[3], px[2], px[1], px[0]);
      g_vy[tid] = make_float4(py[3], py[2], py[1], py[0]);
    } else {
      g_vx[tid] = make_float4(px[0], px[1], px[2], px[3]);
      g_vy[tid] = make_float4(py[0], py[1], py[2], py[3]);
    }
    float half = fmaxf(w, hh) * 0.5f;
    float sx1 = cxx - half, sy1 = cyy - half, sx2 = cxx + half, sy2 = cyy + half;
    g_sqv[tid] = make_float4(sx1, sy1, sx2, sy2);
    g_meta[tid] = make_float2((sx2 - sx1) * (sy2 - sy1), 0.5f * fabsf(s2));
  }

  // anchor prep, vectorized load; all 4 sub-threads compute redundantly,
  // h==0 publishes
  const float* an = anchors + ia * 5;
  float4 av = *reinterpret_cast<const float4*>(an);
  float ax1 = av.x, ay1 = av.y, ax2 = av.z, ay2 = av.w, at = an[4];
  float acx = (ax1 + ax2) * 0.5f, acy = (ay1 + ay2) * 0.5f;
  float aw = ax2 - ax1, ah = ay2 - ay1;
  float ath = at * DEG2RAD;
  float ac = __cosf(ath), asn = __sinf(ath);
  {
    const float ddx[4] = {-0.5f, 0.5f, 0.5f, -0.5f};
    const float ddy[4] = {-0.5f, -0.5f, 0.5f, 0.5f};
    float apx[4], apy[4];
#pragma unroll
    for (int k = 0; k < 4; ++k) {
      apx[k] = acx + ddx[k] * aw * ac - ddy[k] * ah * asn;
      apy[k] = acy + ddx[k] * aw * asn + ddy[k] * ah * ac;
    }
    float s2a = 0.f;
#pragma unroll
    for (int k = 0; k < 4; ++k)
      s2a += apx[k] * apy[(k + 1) & 3] - apx[(k + 1) & 3] * apy[k];
    if (s2a < 0.f) {  // orient CCW (reference reverses)
      float tx = apx[0], ty = apy[0];
      apx[0] = apx[3]; apy[0] = apy[3]; apx[3] = tx; apy[3] = ty;
      tx = apx[1]; ty = apy[1];
      apx[1] = apx[2]; apy[1] = apy[2]; apx[2] = tx; apy[2] = ty;
    }
    if (h == 0) {
      a_qx[la] = make_float4(apx[0], apx[1], apx[2], apx[3]);
      a_qy[la] = make_float4(apy[0], apy[1], apy[2], apy[3]);
      a_area[la] = 0.5f * fabsf(s2a);
    }
  }
  float half = fmaxf(aw, ah) * 0.5f;
  float asx1 = acx - half, asy1 = acy - half, asx2 = acx + half, asy2 = acy + half;
  float asarea = (asx2 - asx1) * (asy2 - asy1);
  __syncthreads();

  // gate phase: h handles 8 of 32 GTs; ballot-compacted push (one atomic
  // per wave per iteration instead of ~per-survivor same-address atomics)
#pragma unroll
  for (int gg = 0; gg < G_N / H_N; ++gg) {
    int g = h * (G_N / H_N) + gg;
    float4 sq = g_sqv[g];
    float2 meta = g_meta[g];
    float ltx = fmaxf(asx1, sq.x);
    float lty = fmaxf(asy1, sq.y);
    float rbx = fminf(asx2, sq.z);
    float rby = fminf(asy2, sq.w);
    float iw = fmaxf(rbx - ltx, 0.f);
    float ih = fmaxf(rby - lty, 0.f);
    float inter_s = iw * ih;
    float ind = inter_s / (asarea + meta.x - inter_s + 1e-6f);
    float4 vx = g_vx[g], vy = g_vy[g];
    float cr0 = (vx.y - vx.x) * (acy - vy.x) - (vy.y - vy.x) * (acx - vx.x);
    float cr1 = (vx.z - vx.y) * (acy - vy.y) - (vy.z - vy.y) * (acx - vx.y);
    float cr2 = (vx.w - vx.z) * (acy - vy.z) - (vy.w - vy.z) * (acx - vx.z);
    float cr3 = (vx.x - vx.w) * (acy - vy.w) - (vy.x - vy.w) * (acx - vx.w);
    bool pall = (cr0 >= 0.f) & (cr1 >= 0.f) & (cr2 >= 0.f) & (cr3 >= 0.f);
    bool nall = (cr0 <= 0.f) & (cr1 <= 0.f) & (cr2 <= 0.f) & (cr3 <= 0.f);
    bool surv = (pall || nall) && (ind > 0.1f);
    ull bal = __ballot(surv);
    if (bal) {
      int base = 0;
      if (ln == 0) base = atomicAdd(&cnt, __popcll(bal));
      base = __shfl(base, 0);
      if (surv) {
        int pre = __popcll(bal & ((1ull << ln) - 1ull));
        list[base + pre] = (unsigned short)((la << 5) | g);
      }
    }
  }
  __syncthreads();

  // clip phase: drain queue densely across all 1024 threads
  int np = cnt;
  for (int i = tid; i < np; i += TPB) {
    int ent = list[i];
    int ca = ent >> 5, g = ent & 31;
    float4 aqx = a_qx[ca], aqy = a_qy[ca];
    float PX[8], PY[8];
    PX[0] = aqx.x; PX[1] = aqx.y; PX[2] = aqx.z; PX[3] = aqx.w;
    PY[0] = aqy.x; PY[1] = aqy.y; PY[2] = aqy.z; PY[3] = aqy.w;
#pragma unroll
    for (int k = 4; k < 8; ++k) { PX[k] = 0.f; PY[k] = 0.f; }
    float4 gvx = g_vx[g], gvy = g_vy[g];
    int n = 4;
    n = clip_pass<4>(gvx.x, gvy.x, gvx.y - gvx.x, gvy.y - gvy.x, PX, PY, n);
    n = clip_pass<5>(gvx.y, gvy.y, gvx.z - gvx.y, gvy.z - gvy.y, PX, PY, n);
    n = clip_pass<6>(gvx.z, gvy.z, gvx.w - gvx.z, gvy.w - gvy.z, PX, PY, n);
    n = clip_pass<7>(gvx.w, gvy.w, gvx.x - gvx.w, gvy.x - gvy.w, PX, PY, n);
    float s = 0.f;
#pragma unroll
    for (int k = 0; k < 8; ++k) {
      if (k < n) {
        float xn = (k + 1 < n) ? PX[(k + 1) & 7] : PX[0];
        float yn = (k + 1 < n) ? PY[(k + 1) & 7] : PY[0];
        s += PX[k] * yn - xn * PY[k];
      }
    }
    float inter = (n >= 3) ? 0.5f * fabsf(s) : 0.f;
    float v = inter / (a_area[ca] + g_meta[g].y - inter + 1e-6f);
    ull pr = ((ull)__float_as_uint(v) << 32) | (unsigned)(~(unsigned)g);
    atomicMax(&rowbest[ca], pr);
    unsigned ga = (unsigned)(blk * APB + ca);
    ull pc = ((ull)__float_as_uint(v) << 32) | (unsigned)(~ga);
    atomicMax(&colmax[g], pc);
  }
  __syncthreads();

  ull rb = rowbest[la];
  float im = __uint_as_float((unsigned)(rb >> 32));
  int arg = (int)(~(unsigned)rb);  // low bits are ~g; init decodes to 0
  int p = (im >= 0.5f) ? 1 : 0;

  if (h == 0) rowpack[ia] = rb;  // for k_fix's forced-anchor delta
  if (tid < G_N)
    gpart[((size_t)j * BPB + blk) * G_N + tid] = colmax[tid];

  // ---- loss phase (uncorrected; fixup handles forced positives) ----
  int lb = lab[arg];
  float csum = 0.f;
  bool bg = (im < 0.4f);
  if (p || bg) {
#pragma unroll
    for (int k = 0; k < 4; ++k) {
      int ci = h * 4 + k;
      if (ci < C_N) {
        float pc = fminf(fmaxf(pcv[k], 1e-4f), 0.9999f);
        bool tgt1 = p && (ci == lb);
        if (tgt1)
          csum += 0.25f * (1.f - pc) * (1.f - pc) * (-__logf(pc + 1e-6f));
        else
          csum += 0.75f * pc * pc * (-__logf(1.f - pc + 1e-6f));
      }
    }
  }

  float rsum = 0.f;
  if (p && h == 0) {
    float t5[5];
    t5[0] = (gcx[arg] - acx) / aw;
    t5[1] = (gcy[arg] - acy) / ah;
    t5[2] = __logf(gw2[arg] / aw);
    t5[3] = __logf(gh2[arg] / ah);
    t5[4] = (gth[arg] - at) * DEG2RAD;
#pragma unroll
    for (int i = 0; i < 5; ++i) {
      float d = fabsf(rvv[i] - t5[i]);
      rsum += (d < BETA) ? (0.5f * d * d / BETA) : (d - 0.5f * BETA);
    }
  }
  int pcnt = (h == 0) ? p : 0;

  // wave shuffle-reduce, then 16 wave partials -> block partial
  float v1 = csum, v2 = rsum;
  int v3 = pcnt;
#pragma unroll
  for (int off = 32; off; off >>= 1) {
    v1 += __shfl_xor(v1, off);
    v2 += __shfl_xor(v2, off);
    v3 += __shfl_xor(v3, off);
  }
  int wv = tid >> 6;
  if (ln == 0) { w1[wv] = v1; w2[wv] = v2; w3[wv] = v3; }
  __syncthreads();
  if (tid == 0) {
    float t1 = 0.f, t2 = 0.f;
    int t3 = 0;
#pragma unroll
    for (int k = 0; k < 16; ++k) { t1 += w1[k]; t2 += w2[k]; t3 += w3[k]; }
    cls_part[blockIdx.x] = t1;
    reg_part[blockIdx.x] = t2;
    cnt_part[blockIdx.x] = t3;
  }
}

// Tiny fixup: resolve forced positives (column argmax over all blocks),
// apply exact per-anchor loss deltas, reduce partials, write output.
__global__ __launch_bounds__(256) void k_fix(
    const float* __restrict__ cls_in, const float* __restrict__ reg_in,
    const float* __restrict__ anchors, const float* __restrict__ annot,
    const ull* __restrict__ gpart, const ull* __restrict__ rowpack,
    const float* __restrict__ cls_part, const float* __restrict__ reg_part,
    const int* __restrict__ cnt_part, float* __restrict__ out, int B) {
  int tid = threadIdx.x;
  __shared__ ull sred[8][G_N];
  __shared__ int fanchor[G_N];
  __shared__ float dcs[G_N], drs[G_N];
  __shared__ int dct[G_N];
  __shared__ float bd_c[8], bd_r[8];  // per-batch delta sums (B<=8)
  __shared__ int bd_n[8];
  __shared__ float s1[256], s2[256];
  __shared__ int s3[256];

  for (int j = 0; j < B; ++j) {
    // reduce per-block column maxima: 8 chunks x 16 blocks
    {
      int g = tid & 31, chunk = tid >> 5;
      const ull* gp = gpart + (size_t)j * BPB * G_N;
      ull m = 0;
#pragma unroll
      for (int b = 0; b < BPB / 8; ++b) {
        ull v = gp[(size_t)(chunk * (BPB / 8) + b) * G_N + g];
        m = v > m ? v : m;
      }
      sred[chunk][g] = m;
    }
    __syncthreads();
    if (tid < G_N) {
      ull m = sred[0][tid];
#pragma unroll
      for (int c = 1; c < 8; ++c) m = sred[c][tid] > m ? sred[c][tid] : m;
      float v = __uint_as_float((unsigned)(m >> 32));
      fanchor[tid] = (v < 0.5f) ? (int)(~(unsigned)m) : -1;
      dcs[tid] = 0.f; drs[tid] = 0.f; dct[tid] = 0;
    }
    __syncthreads();
    if (tid < G_N) {
      int af = fanchor[tid];
      bool owner = (af >= 0);
      for (int g2 = 0; g2 < tid; ++g2)  // parallel dedup: first owner wins
        owner = owner && (fanchor[g2] != af);
      if (owner) {
        size_t ia = (size_t)j * A_N + af;
        ull rb = rowpack[ia];
        float im = __uint_as_float((unsigned)(rb >> 32));
        if (im < 0.5f) {  // p flips 0 -> 1: add exact loss delta
          int arg = (int)(~(unsigned)rb);
          const float* gg = annot + ((size_t)j * G_N + arg) * 6;
          int lb = (int)gg[5];
          const float* c = cls_in + ia * C_N;
          bool bg = (im < 0.4f);
          float ca = 0.f, cb = 0.f;
#pragma unroll
          for (int ci = 0; ci < C_N; ++ci) {
            float pc = fminf(fmaxf(c[ci], 1e-4f), 0.9999f);
            float neg = 0.75f * pc * pc * (-__logf(1.f - pc + 1e-6f));
            if (ci == lb)
              ca += 0.25f * (1.f - pc) * (1.f - pc) * (-__logf(pc + 1e-6f));
            else
              ca += neg;
            if (bg) cb += neg;
          }
          const float* an = anchors + ia * 5;
          float acx = (an[0] + an[2]) * 0.5f, acy = (an[1] + an[3]) * 0.5f;
          float aw = an[2] - an[0], ah = an[3] - an[1];
          float gcxv = (gg[0] + gg[2]) * 0.5f, gcyv = (gg[1] + gg[3]) * 0.5f;
          float gwv = gg[2] - gg[0], ghv = gg[3] - gg[1];
          const float* r = reg_in + ia * 5;
          float t5[5];
          t5[0] = (gcxv - acx) / aw;
          t5[1] = (gcyv - acy) / ah;
          t5[2] = __logf(gwv / aw);
          t5[3] = __logf(ghv / ah);
          t5[4] = (gg[4] - an[4]) * DEG2RAD;
          float rs = 0.f;
#pragma unroll
          for (int i = 0; i < 5; ++i) {
            float d = fabsf(r[i] - t5[i]);
            rs += (d < BETA) ? (0.5f * d * d / BETA) : (d - 0.5f * BETA);
          }
          dcs[tid] = ca - cb;
          drs[tid] = rs;
          dct[tid] = 1;
        }
      }
    }
    __syncthreads();
    if (tid == 0) {  // fixed-order delta sum
      float dc = 0.f, dr = 0.f;
      int dn = 0;
#pragma unroll
      for (int g = 0; g < G_N; ++g) { dc += dcs[g]; dr += drs[g]; dn += dct[g]; }
      bd_c[j] = dc; bd_r[j] = dr; bd_n[j] = dn;
    }
    __syncthreads();
  }

  // reduce per-block partials (B*BPB <= 256 entries)
  int P = B * BPB;
  float cv = 0.f, rvv = 0.f;
  int nv = 0;
  if (tid < P) { cv = cls_part[tid]; rvv = reg_part[tid]; nv = cnt_part[tid]; }
  s1[tid] = cv; s2[tid] = rvv; s3[tid] = nv;
  __syncthreads();
  for (int o = 64; o; o >>= 1) {
    if ((tid & 127) < o) {
      s1[tid] += s1[tid + o]; s2[tid] += s2[tid + o]; s3[tid] += s3[tid + o];
    }
    __syncthreads();
  }
  if (tid == 0) {
    float cl = 0.f, rl = 0.f;
    for (int jj = 0; jj < B; ++jj) {
      float cs = s1[jj * 128] + bd_c[jj];
      float rs = s2[jj * 128] + bd_r[jj];
      int np = s3[jj * 128] + bd_n[jj];
      float npf = (np > 0) ? (float)np : 1.f;
      cl += cs / npf;
      rl += (np > 0) ? rs / (npf * 5.f) : 0.f;
    }
    out[0] = 5.0f * cl / (float)B;
    out[1] = 2.0f * rl / (float)B;
  }
}

extern "C" void kernel_launch(void* const* d_in, const int* in_sizes, int n_in,
                              void* d_out, int out_size, void* d_ws, size_t ws_size,
                              hipStream_t stream) {
  const float* cls = (const float*)d_in[0];
  const float* reg = (const float*)d_in[1];
  const float* anc = (const float*)d_in[2];
  const float* ann = (const float*)d_in[3];
  int B = in_sizes[3] / (G_N * 6);

  char* w = (char*)d_ws;
  ull* gpart = (ull*)w;        w += (size_t)B * BPB * G_N * sizeof(ull);
  ull* rowpack = (ull*)w;      w += (size_t)B * A_N * sizeof(ull);
  float* cls_part = (float*)w; w += (size_t)B * BPB * 4;
  float* reg_part = (float*)w; w += (size_t)B * BPB * 4;
  int* cnt_part = (int*)w;     w += (size_t)B * BPB * 4;

  k_fused<<<B * BPB, TPB, 0, stream>>>(cls, reg, anc, ann, gpart, rowpack,
                                       cls_part, reg_part, cnt_part);
  k_fix<<<1, 256, 0, stream>>>(cls, reg, anc, ann, gpart, rowpack,
                               cls_part, reg_part, cnt_part, (float*)d_out, B);
}